// Round 2
// baseline (14603.026 us; speedup 1.0000x reference)
//
#include <hip/hip_runtime.h>
#include <hip/hip_bf16.h>
#include <stdint.h>

// ACT (adaptive computation time) on MI355X.
// fp32 compute throughout (halting decisions q>0.99 need ~1e-6 reproducibility
// vs the numpy fp32 reference -> bf16 MFMA would flip positions' halting
// step and fail n_updates). Halted positions are skipped via per-iteration
// compaction (active list built by the ponder kernel).
// Dtype (bf16 vs fp32 in/out) is detected at runtime from mask[0] bits.
//
// R1: fp32 SGEMM rework. R0 counters: Occupancy 11.9% (1 wave/SIMD; arch+acc
// regs crossed 256), VALUBusy 46%, 4.6e7 LDS bank-conflict cycles (Bs reads
// at tx*8 -> 4-way; As transpose stores -> 4-way). Fixes: launch_bounds
// (256,2); B fragment split tx*4 / 64+tx*4 (2-way = free); As padded to 132.

#define THR (1.0f - 0.01f)
typedef float4 f4;
#define AP 132  // padded As leading dim (+4: transpose-store banks 2-way)

__device__ __forceinline__ float ld_in(const void* p, long i, int bf) {
  if (bf) {
    unsigned short u = ((const unsigned short*)p)[i];
    return __uint_as_float(((unsigned int)u) << 16);
  }
  return ((const float*)p)[i];
}
__device__ __forceinline__ f4 ld4(const float* p) { return *(const f4*)p; }

#define ADD4(d, s, e) \
  d.x = s.x + e.x; d.y = s.y + e.y; d.z = s.z + e.z; d.w = s.w + e.w;

// ---------- dtype detect + small param conversion ----------
__global__ void k_detect(const void* mask, int* flag, const void* emb,
                         const void* Wp, const void* bp, const void* b1,
                         const void* b2, float* embF, float* WpF, float* bpF,
                         float* b1F, float* b2F) {
  __shared__ int sbf;
  if (threadIdx.x == 0) {
    unsigned int u = ((const unsigned int*)mask)[0];
    int bf = (u == 0x3F803F80u) ? 1 : 0;  // two bf16 1.0s vs fp32 1.0
    *flag = bf;
    sbf = bf;
  }
  __syncthreads();
  int bf = sbf;
  for (int i = threadIdx.x; i < 11 * 512; i += 256) embF[i] = ld_in(emb, i, bf);
  for (int i = threadIdx.x; i < 512; i += 256) WpF[i] = ld_in(Wp, i, bf);
  for (int i = threadIdx.x; i < 2048; i += 256) b1F[i] = ld_in(b1, i, bf);
  for (int i = threadIdx.x; i < 512; i += 256) b2F[i] = ld_in(b2, i, bf);
  if (threadIdx.x == 0) bpF[0] = ld_in(bp, 0, bf);
}

// ---------- big conversions + zero init ----------
__global__ void k_init(const void* state, const void* W1, const void* W2,
                       const void* mask, const int* flag, float* stateF,
                       float* W1F, float* W2F, float* maskF, float* prevF,
                       float* hp, float* rem, float* nup, int* counts) {
  int bf = *flag;
  long t = (long)blockIdx.x * blockDim.x + threadIdx.x;
  long st = (long)gridDim.x * blockDim.x;
  for (long i = t; i < 8388608L; i += st) {
    stateF[i] = ld_in(state, i, bf);
    prevF[i] = 0.f;
  }
  for (long i = t; i < 1048576L; i += st) {
    W1F[i] = ld_in(W1, i, bf);
    W2F[i] = ld_in(W2, i, bf);
  }
  for (long i = t; i < 16384L; i += st) {
    maskF[i] = ld_in(mask, i, bf);
    hp[i] = 0.f;
    rem[i] = 0.f;
    nup[i] = 0.f;
  }
  if (t < 11) counts[t] = 0;
}

// ---------- pondering + halting update + compaction (1 wave / position) ----
__global__ __launch_bounds__(256) void k_ponder(
    const float* __restrict__ stateF, const float* __restrict__ embF,
    const float* __restrict__ WpF, const float* __restrict__ bpF, float* hp,
    float* rem, float* nup, float* uw, int* __restrict__ count,
    int* __restrict__ ridx, int t) {
  int lane = threadIdx.x & 63;
  int pos = blockIdx.x * 4 + (threadIdx.x >> 6);
  float hpv = hp[pos];
  if (hpv >= 1.0f) return;  // halted forever: nothing can change
  const float* s = stateF + (long)pos * 512;
  const float* e = embF + t * 512;
  int d = lane * 8;
  f4 s0 = ld4(s + d), s1 = ld4(s + d + 4);
  f4 e0 = ld4(e + d), e1 = ld4(e + d + 4);
  f4 w0 = ld4(WpF + d), w1 = ld4(WpF + d + 4);
  float acc = (s0.x + e0.x) * w0.x;
  acc = fmaf(s0.y + e0.y, w0.y, acc);
  acc = fmaf(s0.z + e0.z, w0.z, acc);
  acc = fmaf(s0.w + e0.w, w0.w, acc);
  acc = fmaf(s1.x + e1.x, w1.x, acc);
  acc = fmaf(s1.y + e1.y, w1.y, acc);
  acc = fmaf(s1.z + e1.z, w1.z, acc);
  acc = fmaf(s1.w + e1.w, w1.w, acc);
#pragma unroll
  for (int off = 32; off > 0; off >>= 1) acc += __shfl_xor(acc, off, 64);
  if (lane == 0) {
    float p = 1.0f / (1.0f + expf(-(acc + bpF[0])));
    // exact fp32 mirror of the reference's scalar chain (still==1 here)
    float q = hpv + p;
    float nh = (q > THR) ? 1.0f : 0.0f;
    float st2 = (q <= THR) ? 1.0f : 0.0f;
    float hpn = hpv + p * st2;
    float remn = rem[pos] + nh * (1.0f - hpn);
    hpn = hpn + nh * remn;
    nup[pos] = nup[pos] + st2 + nh;
    uw[pos] = p * st2 + nh * remn;
    hp[pos] = hpn;
    rem[pos] = remn;
    int idx = atomicAdd(count, 1);
    ridx[idx] = pos;
  }
}

#define STORE_TILE(buf)                                                        \
  As[buf][kq4 + 0][ra] = a0.x; As[buf][kq4 + 1][ra] = a0.y;                    \
  As[buf][kq4 + 2][ra] = a0.z; As[buf][kq4 + 3][ra] = a0.w;                    \
  As[buf][kq4 + 0][ra + 64] = a1.x; As[buf][kq4 + 1][ra + 64] = a1.y;          \
  As[buf][kq4 + 2][ra + 64] = a1.z; As[buf][kq4 + 3][ra + 64] = a1.w;          \
  *(f4*)&Bs[buf][kb1][nb] = b0; *(f4*)&Bs[buf][kb2][nb] = b1;

// A rows: ty*4+i and 64+ty*4+i (broadcast, conflict-free).
// B cols: tx*4+j and 64+tx*4+j (16 f4 in 256B = 2-way = free).
#define FMA_BLOCK(cur)                                                         \
  _Pragma("unroll") for (int k = 0; k < 16; k++) {                             \
    float av[8], bv[8];                                                        \
    *(f4*)(av + 0) = *(const f4*)&As[cur][k][ty4];                             \
    *(f4*)(av + 4) = *(const f4*)&As[cur][k][64 + ty4];                        \
    *(f4*)(bv + 0) = *(const f4*)&Bs[cur][k][tx4];                             \
    *(f4*)(bv + 4) = *(const f4*)&Bs[cur][k][64 + tx4];                        \
    _Pragma("unroll") for (int i = 0; i < 8; i++)                              \
        _Pragma("unroll") for (int j = 0; j < 8; j++) acc[i][j] =              \
        fmaf(av[i], bv[j], acc[i][j]);                                         \
  }

// ---------- GEMM1: U = relu((state[ridx]+emb) * W1 + b1), K=512, N=2048 ----
__global__ __launch_bounds__(256, 2) void k_gemm1(
    const float* __restrict__ stateF, const float* __restrict__ embT,
    const float* __restrict__ W, const float* __restrict__ bias,
    const int* __restrict__ count, const int* __restrict__ ridx,
    float* __restrict__ U, int c0, int mc) {
  const int NN = 2048, KT = 32;
  int Ma = *count;
  int mEnd = c0 + mc;
  if (Ma < mEnd) mEnd = Ma;
  int m0 = c0 + blockIdx.x * 128;
  if (m0 >= mEnd) return;
  int n0 = blockIdx.y * 128;
  __shared__ float As[2][16][AP];
  __shared__ float Bs[2][16][128];
  int tid = threadIdx.x;
  int ra = tid >> 2;
  int kq4 = (tid & 3) << 2;
  int r1 = m0 + ra, r2 = r1 + 64;
  long p1 = (r1 < mEnd) ? (long)ridx[r1] : -1;
  long p2 = (r2 < mEnd) ? (long)ridx[r2] : -1;
  int kb1 = tid >> 5, kb2 = kb1 + 8;
  int nb = (tid & 31) << 2;
  const float* Bp = W + n0 + nb;
  f4 a0, a1, b0, b1;
  f4 zero = make_float4(0.f, 0.f, 0.f, 0.f);
  {
    f4 e = ld4(embT + kq4);
    a0 = zero; a1 = zero;
    if (p1 >= 0) { f4 s = ld4(stateF + p1 * 512 + kq4); ADD4(a0, s, e); }
    if (p2 >= 0) { f4 s = ld4(stateF + p2 * 512 + kq4); ADD4(a1, s, e); }
    b0 = ld4(Bp + (long)kb1 * NN);
    b1 = ld4(Bp + (long)kb2 * NN);
  }
  STORE_TILE(0);
  __syncthreads();
  float acc[8][8];
#pragma unroll
  for (int i = 0; i < 8; i++)
#pragma unroll
    for (int j = 0; j < 8; j++) acc[i][j] = 0.f;
  int tx4 = (tid & 15) << 2, ty4 = (tid >> 4) << 2;
#pragma unroll 1
  for (int kt = 0; kt < KT; ++kt) {
    int cur = kt & 1, nxt = cur ^ 1;
    if (kt + 1 < KT) {
      int kg = ((kt + 1) << 4) + kq4;
      f4 e = ld4(embT + kg);
      a0 = zero; a1 = zero;
      if (p1 >= 0) { f4 s = ld4(stateF + p1 * 512 + kg); ADD4(a0, s, e); }
      if (p2 >= 0) { f4 s = ld4(stateF + p2 * 512 + kg); ADD4(a1, s, e); }
      b0 = ld4(Bp + (long)(((kt + 1) << 4) + kb1) * NN);
      b1 = ld4(Bp + (long)(((kt + 1) << 4) + kb2) * NN);
    }
    FMA_BLOCK(cur);
    if (kt + 1 < KT) { STORE_TILE(nxt); }
    __syncthreads();
  }
  f4 bb0 = ld4(bias + n0 + tx4);
  f4 bb1 = ld4(bias + n0 + 64 + tx4);
#pragma unroll
  for (int i = 0; i < 8; i++) {
    int row = (i < 4) ? (ty4 + i) : (64 + ty4 + i - 4);
    int r = m0 + row;
    if (r < mEnd) {
      float* dst = U + (long)(r - c0) * 2048 + n0;
      f4 o0, o1;
      o0.x = fmaxf(acc[i][0] + bb0.x, 0.f);
      o0.y = fmaxf(acc[i][1] + bb0.y, 0.f);
      o0.z = fmaxf(acc[i][2] + bb0.z, 0.f);
      o0.w = fmaxf(acc[i][3] + bb0.w, 0.f);
      o1.x = fmaxf(acc[i][4] + bb1.x, 0.f);
      o1.y = fmaxf(acc[i][5] + bb1.y, 0.f);
      o1.z = fmaxf(acc[i][6] + bb1.z, 0.f);
      o1.w = fmaxf(acc[i][7] + bb1.w, 0.f);
      *(f4*)(dst + tx4) = o0;
      *(f4*)(dst + 64 + tx4) = o1;
    }
  }
}

// ---------- GEMM2: h = U*W2 + b2; state=h*mask; prev += h*uw. K=2048,N=512 --
__global__ __launch_bounds__(256, 2) void k_gemm2(
    const float* __restrict__ U, const float* __restrict__ W,
    const float* __restrict__ bias, const int* __restrict__ count,
    const int* __restrict__ ridx, const float* __restrict__ maskF,
    const float* __restrict__ uwF, float* __restrict__ stateF,
    float* __restrict__ prevF, int c0, int mc) {
  const int NN = 512, KT = 128;
  int Ma = *count;
  int mEnd = c0 + mc;
  if (Ma < mEnd) mEnd = Ma;
  int m0 = c0 + blockIdx.x * 128;
  if (m0 >= mEnd) return;
  int n0 = blockIdx.y * 128;
  __shared__ float As[2][16][AP];
  __shared__ float Bs[2][16][128];
  int tid = threadIdx.x;
  int ra = tid >> 2;
  int kq4 = (tid & 3) << 2;
  int r1 = m0 + ra, r2 = r1 + 64;
  long q1 = (r1 < mEnd) ? (long)(r1 - c0) : -1;
  long q2 = (r2 < mEnd) ? (long)(r2 - c0) : -1;
  int kb1 = tid >> 5, kb2 = kb1 + 8;
  int nb = (tid & 31) << 2;
  const float* Bp = W + n0 + nb;
  f4 a0, a1, b0, b1;
  f4 zero = make_float4(0.f, 0.f, 0.f, 0.f);
  {
    a0 = (q1 >= 0) ? ld4(U + q1 * 2048 + kq4) : zero;
    a1 = (q2 >= 0) ? ld4(U + q2 * 2048 + kq4) : zero;
    b0 = ld4(Bp + (long)kb1 * NN);
    b1 = ld4(Bp + (long)kb2 * NN);
  }
  STORE_TILE(0);
  __syncthreads();
  float acc[8][8];
#pragma unroll
  for (int i = 0; i < 8; i++)
#pragma unroll
    for (int j = 0; j < 8; j++) acc[i][j] = 0.f;
  int tx4 = (tid & 15) << 2, ty4 = (tid >> 4) << 2;
#pragma unroll 1
  for (int kt = 0; kt < KT; ++kt) {
    int cur = kt & 1, nxt = cur ^ 1;
    if (kt + 1 < KT) {
      int kg = ((kt + 1) << 4) + kq4;
      a0 = (q1 >= 0) ? ld4(U + q1 * 2048 + kg) : zero;
      a1 = (q2 >= 0) ? ld4(U + q2 * 2048 + kg) : zero;
      b0 = ld4(Bp + (long)(((kt + 1) << 4) + kb1) * NN);
      b1 = ld4(Bp + (long)(((kt + 1) << 4) + kb2) * NN);
    }
    FMA_BLOCK(cur);
    if (kt + 1 < KT) { STORE_TILE(nxt); }
    __syncthreads();
  }
  f4 bb0 = ld4(bias + n0 + tx4);
  f4 bb1 = ld4(bias + n0 + 64 + tx4);
#pragma unroll
  for (int i = 0; i < 8; i++) {
    int row = (i < 4) ? (ty4 + i) : (64 + ty4 + i - 4);
    int r = m0 + row;
    if (r < mEnd) {
      long pos = (long)ridx[r];
      float mk = maskF[pos];
      float uv = uwF[pos];
      float* sp = stateF + pos * 512 + n0;
      float* pp = prevF + pos * 512 + n0;
      f4 h0, h1;
      h0.x = (acc[i][0] + bb0.x) * mk;
      h0.y = (acc[i][1] + bb0.y) * mk;
      h0.z = (acc[i][2] + bb0.z) * mk;
      h0.w = (acc[i][3] + bb0.w) * mk;
      h1.x = (acc[i][4] + bb1.x) * mk;
      h1.y = (acc[i][5] + bb1.y) * mk;
      h1.z = (acc[i][6] + bb1.z) * mk;
      h1.w = (acc[i][7] + bb1.w) * mk;
      f4 p0 = ld4(pp + tx4), p1v = ld4(pp + 64 + tx4);
      p0.x = fmaf(h0.x, uv, p0.x);
      p0.y = fmaf(h0.y, uv, p0.y);
      p0.z = fmaf(h0.z, uv, p0.z);
      p0.w = fmaf(h0.w, uv, p0.w);
      p1v.x = fmaf(h1.x, uv, p1v.x);
      p1v.y = fmaf(h1.y, uv, p1v.y);
      p1v.z = fmaf(h1.z, uv, p1v.z);
      p1v.w = fmaf(h1.w, uv, p1v.w);
      *(f4*)(sp + tx4) = h0;
      *(f4*)(sp + 64 + tx4) = h1;
      *(f4*)(pp + tx4) = p0;
      *(f4*)(pp + 64 + tx4) = p1v;
    }
  }
}

// ---------- final: concat outputs, cast per detected dtype ----------
__global__ void k_final(const float* prevF, const float* nupF,
                        const float* remF, void* out, const int* flag) {
  long i = (long)blockIdx.x * 256 + threadIdx.x;
  if (i >= 8421376L) return;
  float v;
  if (i < 8388608L) v = prevF[i];
  else if (i < 8404992L) v = nupF[i - 8388608L];
  else v = remF[i - 8404992L];
  if (*flag) ((__hip_bfloat16*)out)[i] = __float2bfloat16(v);
  else ((float*)out)[i] = v;
}

extern "C" void kernel_launch(void* const* d_in, const int* in_sizes, int n_in,
                              void* d_out, int out_size, void* d_ws,
                              size_t ws_size, hipStream_t stream) {
  const void* state = d_in[0];
  const void* mask = d_in[1];
  const void* emb = d_in[2];
  const void* Wp = d_in[3];
  const void* bp = d_in[4];
  const void* W1 = d_in[5];
  const void* b1 = d_in[6];
  const void* W2 = d_in[7];
  const void* b2 = d_in[8];
  char* w = (char*)d_ws;
  float* stateF = (float*)(w + 0L);
  float* prevF = (float*)(w + 33554432L);
  float* W1F = (float*)(w + 67108864L);
  float* W2F = (float*)(w + 71303168L);
  float* maskF = (float*)(w + 75497472L);
  float* hp = (float*)(w + 75563008L);
  float* rem = (float*)(w + 75628544L);
  float* nup = (float*)(w + 75694080L);
  float* uwf = (float*)(w + 75759616L);
  float* embF = (float*)(w + 75825152L);
  float* WpF = (float*)(w + 75849728L);
  float* b1F = (float*)(w + 75851776L);
  float* b2F = (float*)(w + 75859968L);
  float* bpF = (float*)(w + 75862016L);
  int* flag = (int*)(w + 75862272L);
  int* counts = (int*)(w + 75862528L);
  int* ridx = (int*)(w + 75863552L);
  float* U = (float*)(w + 76584448L);
  // U chunk size from remaining workspace (multiple of 128 rows of 2048 fp32)
  long ub = (long)ws_size - 76584448L;
  long rows = ub / (2048L * 4L);
  long McL = rows & ~127L;
  if (McL > 16384L) McL = 16384L;
  if (McL < 128L) McL = 128L;
  int Mc = (int)McL;
  int nCh = (16384 + Mc - 1) / Mc;

  k_detect<<<1, 256, 0, stream>>>(mask, flag, emb, Wp, bp, b1, b2, embF, WpF,
                                  bpF, b1F, b2F);
  k_init<<<2048, 256, 0, stream>>>(state, W1, W2, mask, flag, stateF, W1F, W2F,
                                   maskF, prevF, hp, rem, nup, counts);
  for (int t = 0; t <= 10; t++) {
    k_ponder<<<4096, 256, 0, stream>>>(stateF, embF, WpF, bpF, hp, rem, nup,
                                       uwf, counts + t, ridx + (long)t * 16384,
                                       t);
    for (int c = 0; c < nCh; c++) {
      int c0 = c * Mc;
      int mc = 16384 - c0;
      if (mc > Mc) mc = Mc;
      dim3 g1(mc / 128, 16), g2(mc / 128, 4);
      k_gemm1<<<g1, 256, 0, stream>>>(stateF, embF + t * 512, W1F, b1F,
                                      counts + t, ridx + (long)t * 16384, U, c0,
                                      mc);
      k_gemm2<<<g2, 256, 0, stream>>>(U, W2F, b2F, counts + t,
                                      ridx + (long)t * 16384, maskF, uwf,
                                      stateF, prevF, c0, mc);
    }
  }
  k_final<<<32896, 256, 0, stream>>>(prevF, nup, rem, d_out, flag);
}

// Round 3
// 4200.338 us; speedup vs baseline: 3.4766x; 3.4766x over previous
//
#include <hip/hip_runtime.h>
#include <hip/hip_bf16.h>
#include <stdint.h>

// ACT (adaptive computation time) on MI355X.
// fp32 compute throughout (halting decisions q>0.99 need ~1e-6 reproducibility
// vs the numpy fp32 reference -> bf16 MFMA would flip positions' halting
// step and fail n_updates). Halted positions are skipped via per-iteration
// compaction (active list built by the ponder kernel).
// Dtype (bf16 vs fp32 in/out) is detected at runtime from mask[0] bits.
//
// R2 post-mortem: __launch_bounds__(256,2) made the compiler cap VGPRs at 128
// -> 64-reg accumulator spilled to scratch -> 10 GB/dispatch HBM traffic,
// 3.2x regression. REVERTED to plain (256). The R2 bank-conflict fixes are
// KEPT (confirmed: SQ_LDS_BANK_CONFLICT 4.6e7 -> 4.2e6): B fragment split
// tx*4 / 64+tx*4 (2-way = free), As leading dim padded 128->132.

#define THR (1.0f - 0.01f)
typedef float4 f4;
#define AP 132  // padded As leading dim (+4: transpose-store banks 2-way)

__device__ __forceinline__ float ld_in(const void* p, long i, int bf) {
  if (bf) {
    unsigned short u = ((const unsigned short*)p)[i];
    return __uint_as_float(((unsigned int)u) << 16);
  }
  return ((const float*)p)[i];
}
__device__ __forceinline__ f4 ld4(const float* p) { return *(const f4*)p; }

#define ADD4(d, s, e) \
  d.x = s.x + e.x; d.y = s.y + e.y; d.z = s.z + e.z; d.w = s.w + e.w;

// ---------- dtype detect + small param conversion ----------
__global__ void k_detect(const void* mask, int* flag, const void* emb,
                         const void* Wp, const void* bp, const void* b1,
                         const void* b2, float* embF, float* WpF, float* bpF,
                         float* b1F, float* b2F) {
  __shared__ int sbf;
  if (threadIdx.x == 0) {
    unsigned int u = ((const unsigned int*)mask)[0];
    int bf = (u == 0x3F803F80u) ? 1 : 0;  // two bf16 1.0s vs fp32 1.0
    *flag = bf;
    sbf = bf;
  }
  __syncthreads();
  int bf = sbf;
  for (int i = threadIdx.x; i < 11 * 512; i += 256) embF[i] = ld_in(emb, i, bf);
  for (int i = threadIdx.x; i < 512; i += 256) WpF[i] = ld_in(Wp, i, bf);
  for (int i = threadIdx.x; i < 2048; i += 256) b1F[i] = ld_in(b1, i, bf);
  for (int i = threadIdx.x; i < 512; i += 256) b2F[i] = ld_in(b2, i, bf);
  if (threadIdx.x == 0) bpF[0] = ld_in(bp, 0, bf);
}

// ---------- big conversions + zero init ----------
__global__ void k_init(const void* state, const void* W1, const void* W2,
                       const void* mask, const int* flag, float* stateF,
                       float* W1F, float* W2F, float* maskF, float* prevF,
                       float* hp, float* rem, float* nup, int* counts) {
  int bf = *flag;
  long t = (long)blockIdx.x * blockDim.x + threadIdx.x;
  long st = (long)gridDim.x * blockDim.x;
  for (long i = t; i < 8388608L; i += st) {
    stateF[i] = ld_in(state, i, bf);
    prevF[i] = 0.f;
  }
  for (long i = t; i < 1048576L; i += st) {
    W1F[i] = ld_in(W1, i, bf);
    W2F[i] = ld_in(W2, i, bf);
  }
  for (long i = t; i < 16384L; i += st) {
    maskF[i] = ld_in(mask, i, bf);
    hp[i] = 0.f;
    rem[i] = 0.f;
    nup[i] = 0.f;
  }
  if (t < 11) counts[t] = 0;
}

// ---------- pondering + halting update + compaction (1 wave / position) ----
__global__ __launch_bounds__(256) void k_ponder(
    const float* __restrict__ stateF, const float* __restrict__ embF,
    const float* __restrict__ WpF, const float* __restrict__ bpF, float* hp,
    float* rem, float* nup, float* uw, int* __restrict__ count,
    int* __restrict__ ridx, int t) {
  int lane = threadIdx.x & 63;
  int pos = blockIdx.x * 4 + (threadIdx.x >> 6);
  float hpv = hp[pos];
  if (hpv >= 1.0f) return;  // halted forever: nothing can change
  const float* s = stateF + (long)pos * 512;
  const float* e = embF + t * 512;
  int d = lane * 8;
  f4 s0 = ld4(s + d), s1 = ld4(s + d + 4);
  f4 e0 = ld4(e + d), e1 = ld4(e + d + 4);
  f4 w0 = ld4(WpF + d), w1 = ld4(WpF + d + 4);
  float acc = (s0.x + e0.x) * w0.x;
  acc = fmaf(s0.y + e0.y, w0.y, acc);
  acc = fmaf(s0.z + e0.z, w0.z, acc);
  acc = fmaf(s0.w + e0.w, w0.w, acc);
  acc = fmaf(s1.x + e1.x, w1.x, acc);
  acc = fmaf(s1.y + e1.y, w1.y, acc);
  acc = fmaf(s1.z + e1.z, w1.z, acc);
  acc = fmaf(s1.w + e1.w, w1.w, acc);
#pragma unroll
  for (int off = 32; off > 0; off >>= 1) acc += __shfl_xor(acc, off, 64);
  if (lane == 0) {
    float p = 1.0f / (1.0f + expf(-(acc + bpF[0])));
    // exact fp32 mirror of the reference's scalar chain (still==1 here)
    float q = hpv + p;
    float nh = (q > THR) ? 1.0f : 0.0f;
    float st2 = (q <= THR) ? 1.0f : 0.0f;
    float hpn = hpv + p * st2;
    float remn = rem[pos] + nh * (1.0f - hpn);
    hpn = hpn + nh * remn;
    nup[pos] = nup[pos] + st2 + nh;
    uw[pos] = p * st2 + nh * remn;
    hp[pos] = hpn;
    rem[pos] = remn;
    int idx = atomicAdd(count, 1);
    ridx[idx] = pos;
  }
}

#define STORE_TILE(buf)                                                        \
  As[buf][kq4 + 0][ra] = a0.x; As[buf][kq4 + 1][ra] = a0.y;                    \
  As[buf][kq4 + 2][ra] = a0.z; As[buf][kq4 + 3][ra] = a0.w;                    \
  As[buf][kq4 + 0][ra + 64] = a1.x; As[buf][kq4 + 1][ra + 64] = a1.y;          \
  As[buf][kq4 + 2][ra + 64] = a1.z; As[buf][kq4 + 3][ra + 64] = a1.w;          \
  *(f4*)&Bs[buf][kb1][nb] = b0; *(f4*)&Bs[buf][kb2][nb] = b1;

// A rows: ty*4+i and 64+ty*4+i (broadcast, conflict-free).
// B cols: tx*4+j and 64+tx*4+j (16 f4 in 256B = 2-way = free).
#define FMA_BLOCK(cur)                                                         \
  _Pragma("unroll") for (int k = 0; k < 16; k++) {                             \
    float av[8], bv[8];                                                        \
    *(f4*)(av + 0) = *(const f4*)&As[cur][k][ty4];                             \
    *(f4*)(av + 4) = *(const f4*)&As[cur][k][64 + ty4];                        \
    *(f4*)(bv + 0) = *(const f4*)&Bs[cur][k][tx4];                             \
    *(f4*)(bv + 4) = *(const f4*)&Bs[cur][k][64 + tx4];                        \
    _Pragma("unroll") for (int i = 0; i < 8; i++)                              \
        _Pragma("unroll") for (int j = 0; j < 8; j++) acc[i][j] =              \
        fmaf(av[i], bv[j], acc[i][j]);                                         \
  }

// ---------- GEMM1: U = relu((state[ridx]+emb) * W1 + b1), K=512, N=2048 ----
__global__ __launch_bounds__(256) void k_gemm1(
    const float* __restrict__ stateF, const float* __restrict__ embT,
    const float* __restrict__ W, const float* __restrict__ bias,
    const int* __restrict__ count, const int* __restrict__ ridx,
    float* __restrict__ U, int c0, int mc) {
  const int NN = 2048, KT = 32;
  int Ma = *count;
  int mEnd = c0 + mc;
  if (Ma < mEnd) mEnd = Ma;
  int m0 = c0 + blockIdx.x * 128;
  if (m0 >= mEnd) return;
  int n0 = blockIdx.y * 128;
  __shared__ float As[2][16][AP];
  __shared__ float Bs[2][16][128];
  int tid = threadIdx.x;
  int ra = tid >> 2;
  int kq4 = (tid & 3) << 2;
  int r1 = m0 + ra, r2 = r1 + 64;
  long p1 = (r1 < mEnd) ? (long)ridx[r1] : -1;
  long p2 = (r2 < mEnd) ? (long)ridx[r2] : -1;
  int kb1 = tid >> 5, kb2 = kb1 + 8;
  int nb = (tid & 31) << 2;
  const float* Bp = W + n0 + nb;
  f4 a0, a1, b0, b1;
  f4 zero = make_float4(0.f, 0.f, 0.f, 0.f);
  {
    f4 e = ld4(embT + kq4);
    a0 = zero; a1 = zero;
    if (p1 >= 0) { f4 s = ld4(stateF + p1 * 512 + kq4); ADD4(a0, s, e); }
    if (p2 >= 0) { f4 s = ld4(stateF + p2 * 512 + kq4); ADD4(a1, s, e); }
    b0 = ld4(Bp + (long)kb1 * NN);
    b1 = ld4(Bp + (long)kb2 * NN);
  }
  STORE_TILE(0);
  __syncthreads();
  float acc[8][8];
#pragma unroll
  for (int i = 0; i < 8; i++)
#pragma unroll
    for (int j = 0; j < 8; j++) acc[i][j] = 0.f;
  int tx4 = (tid & 15) << 2, ty4 = (tid >> 4) << 2;
#pragma unroll 1
  for (int kt = 0; kt < KT; ++kt) {
    int cur = kt & 1, nxt = cur ^ 1;
    if (kt + 1 < KT) {
      int kg = ((kt + 1) << 4) + kq4;
      f4 e = ld4(embT + kg);
      a0 = zero; a1 = zero;
      if (p1 >= 0) { f4 s = ld4(stateF + p1 * 512 + kg); ADD4(a0, s, e); }
      if (p2 >= 0) { f4 s = ld4(stateF + p2 * 512 + kg); ADD4(a1, s, e); }
      b0 = ld4(Bp + (long)(((kt + 1) << 4) + kb1) * NN);
      b1 = ld4(Bp + (long)(((kt + 1) << 4) + kb2) * NN);
    }
    FMA_BLOCK(cur);
    if (kt + 1 < KT) { STORE_TILE(nxt); }
    __syncthreads();
  }
  f4 bb0 = ld4(bias + n0 + tx4);
  f4 bb1 = ld4(bias + n0 + 64 + tx4);
#pragma unroll
  for (int i = 0; i < 8; i++) {
    int row = (i < 4) ? (ty4 + i) : (64 + ty4 + i - 4);
    int r = m0 + row;
    if (r < mEnd) {
      float* dst = U + (long)(r - c0) * 2048 + n0;
      f4 o0, o1;
      o0.x = fmaxf(acc[i][0] + bb0.x, 0.f);
      o0.y = fmaxf(acc[i][1] + bb0.y, 0.f);
      o0.z = fmaxf(acc[i][2] + bb0.z, 0.f);
      o0.w = fmaxf(acc[i][3] + bb0.w, 0.f);
      o1.x = fmaxf(acc[i][4] + bb1.x, 0.f);
      o1.y = fmaxf(acc[i][5] + bb1.y, 0.f);
      o1.z = fmaxf(acc[i][6] + bb1.z, 0.f);
      o1.w = fmaxf(acc[i][7] + bb1.w, 0.f);
      *(f4*)(dst + tx4) = o0;
      *(f4*)(dst + 64 + tx4) = o1;
    }
  }
}

// ---------- GEMM2: h = U*W2 + b2; state=h*mask; prev += h*uw. K=2048,N=512 --
__global__ __launch_bounds__(256) void k_gemm2(
    const float* __restrict__ U, const float* __restrict__ W,
    const float* __restrict__ bias, const int* __restrict__ count,
    const int* __restrict__ ridx, const float* __restrict__ maskF,
    const float* __restrict__ uwF, float* __restrict__ stateF,
    float* __restrict__ prevF, int c0, int mc) {
  const int NN = 512, KT = 128;
  int Ma = *count;
  int mEnd = c0 + mc;
  if (Ma < mEnd) mEnd = Ma;
  int m0 = c0 + blockIdx.x * 128;
  if (m0 >= mEnd) return;
  int n0 = blockIdx.y * 128;
  __shared__ float As[2][16][AP];
  __shared__ float Bs[2][16][128];
  int tid = threadIdx.x;
  int ra = tid >> 2;
  int kq4 = (tid & 3) << 2;
  int r1 = m0 + ra, r2 = r1 + 64;
  long q1 = (r1 < mEnd) ? (long)(r1 - c0) : -1;
  long q2 = (r2 < mEnd) ? (long)(r2 - c0) : -1;
  int kb1 = tid >> 5, kb2 = kb1 + 8;
  int nb = (tid & 31) << 2;
  const float* Bp = W + n0 + nb;
  f4 a0, a1, b0, b1;
  f4 zero = make_float4(0.f, 0.f, 0.f, 0.f);
  {
    a0 = (q1 >= 0) ? ld4(U + q1 * 2048 + kq4) : zero;
    a1 = (q2 >= 0) ? ld4(U + q2 * 2048 + kq4) : zero;
    b0 = ld4(Bp + (long)kb1 * NN);
    b1 = ld4(Bp + (long)kb2 * NN);
  }
  STORE_TILE(0);
  __syncthreads();
  float acc[8][8];
#pragma unroll
  for (int i = 0; i < 8; i++)
#pragma unroll
    for (int j = 0; j < 8; j++) acc[i][j] = 0.f;
  int tx4 = (tid & 15) << 2, ty4 = (tid >> 4) << 2;
#pragma unroll 1
  for (int kt = 0; kt < KT; ++kt) {
    int cur = kt & 1, nxt = cur ^ 1;
    if (kt + 1 < KT) {
      int kg = ((kt + 1) << 4) + kq4;
      a0 = (q1 >= 0) ? ld4(U + q1 * 2048 + kg) : zero;
      a1 = (q2 >= 0) ? ld4(U + q2 * 2048 + kg) : zero;
      b0 = ld4(Bp + (long)(((kt + 1) << 4) + kb1) * NN);
      b1 = ld4(Bp + (long)(((kt + 1) << 4) + kb2) * NN);
    }
    FMA_BLOCK(cur);
    if (kt + 1 < KT) { STORE_TILE(nxt); }
    __syncthreads();
  }
  f4 bb0 = ld4(bias + n0 + tx4);
  f4 bb1 = ld4(bias + n0 + 64 + tx4);
#pragma unroll
  for (int i = 0; i < 8; i++) {
    int row = (i < 4) ? (ty4 + i) : (64 + ty4 + i - 4);
    int r = m0 + row;
    if (r < mEnd) {
      long pos = (long)ridx[r];
      float mk = maskF[pos];
      float uv = uwF[pos];
      float* sp = stateF + pos * 512 + n0;
      float* pp = prevF + pos * 512 + n0;
      f4 h0, h1;
      h0.x = (acc[i][0] + bb0.x) * mk;
      h0.y = (acc[i][1] + bb0.y) * mk;
      h0.z = (acc[i][2] + bb0.z) * mk;
      h0.w = (acc[i][3] + bb0.w) * mk;
      h1.x = (acc[i][4] + bb1.x) * mk;
      h1.y = (acc[i][5] + bb1.y) * mk;
      h1.z = (acc[i][6] + bb1.z) * mk;
      h1.w = (acc[i][7] + bb1.w) * mk;
      f4 p0 = ld4(pp + tx4), p1v = ld4(pp + 64 + tx4);
      p0.x = fmaf(h0.x, uv, p0.x);
      p0.y = fmaf(h0.y, uv, p0.y);
      p0.z = fmaf(h0.z, uv, p0.z);
      p0.w = fmaf(h0.w, uv, p0.w);
      p1v.x = fmaf(h1.x, uv, p1v.x);
      p1v.y = fmaf(h1.y, uv, p1v.y);
      p1v.z = fmaf(h1.z, uv, p1v.z);
      p1v.w = fmaf(h1.w, uv, p1v.w);
      *(f4*)(sp + tx4) = h0;
      *(f4*)(sp + 64 + tx4) = h1;
      *(f4*)(pp + tx4) = p0;
      *(f4*)(pp + 64 + tx4) = p1v;
    }
  }
}

// ---------- final: concat outputs, cast per detected dtype ----------
__global__ void k_final(const float* prevF, const float* nupF,
                        const float* remF, void* out, const int* flag) {
  long i = (long)blockIdx.x * 256 + threadIdx.x;
  if (i >= 8421376L) return;
  float v;
  if (i < 8388608L) v = prevF[i];
  else if (i < 8404992L) v = nupF[i - 8388608L];
  else v = remF[i - 8404992L];
  if (*flag) ((__hip_bfloat16*)out)[i] = __float2bfloat16(v);
  else ((float*)out)[i] = v;
}

extern "C" void kernel_launch(void* const* d_in, const int* in_sizes, int n_in,
                              void* d_out, int out_size, void* d_ws,
                              size_t ws_size, hipStream_t stream) {
  const void* state = d_in[0];
  const void* mask = d_in[1];
  const void* emb = d_in[2];
  const void* Wp = d_in[3];
  const void* bp = d_in[4];
  const void* W1 = d_in[5];
  const void* b1 = d_in[6];
  const void* W2 = d_in[7];
  const void* b2 = d_in[8];
  char* w = (char*)d_ws;
  float* stateF = (float*)(w + 0L);
  float* prevF = (float*)(w + 33554432L);
  float* W1F = (float*)(w + 67108864L);
  float* W2F = (float*)(w + 71303168L);
  float* maskF = (float*)(w + 75497472L);
  float* hp = (float*)(w + 75563008L);
  float* rem = (float*)(w + 75628544L);
  float* nup = (float*)(w + 75694080L);
  float* uwf = (float*)(w + 75759616L);
  float* embF = (float*)(w + 75825152L);
  float* WpF = (float*)(w + 75849728L);
  float* b1F = (float*)(w + 75851776L);
  float* b2F = (float*)(w + 75859968L);
  float* bpF = (float*)(w + 75862016L);
  int* flag = (int*)(w + 75862272L);
  int* counts = (int*)(w + 75862528L);
  int* ridx = (int*)(w + 75863552L);
  float* U = (float*)(w + 76584448L);
  // U chunk size from remaining workspace (multiple of 128 rows of 2048 fp32)
  long ub = (long)ws_size - 76584448L;
  long rows = ub / (2048L * 4L);
  long McL = rows & ~127L;
  if (McL > 16384L) McL = 16384L;
  if (McL < 128L) McL = 128L;
  int Mc = (int)McL;
  int nCh = (16384 + Mc - 1) / Mc;

  k_detect<<<1, 256, 0, stream>>>(mask, flag, emb, Wp, bp, b1, b2, embF, WpF,
                                  bpF, b1F, b2F);
  k_init<<<2048, 256, 0, stream>>>(state, W1, W2, mask, flag, stateF, W1F, W2F,
                                   maskF, prevF, hp, rem, nup, counts);
  for (int t = 0; t <= 10; t++) {
    k_ponder<<<4096, 256, 0, stream>>>(stateF, embF, WpF, bpF, hp, rem, nup,
                                       uwf, counts + t, ridx + (long)t * 16384,
                                       t);
    for (int c = 0; c < nCh; c++) {
      int c0 = c * Mc;
      int mc = 16384 - c0;
      if (mc > Mc) mc = Mc;
      dim3 g1(mc / 128, 16), g2(mc / 128, 4);
      k_gemm1<<<g1, 256, 0, stream>>>(stateF, embF + t * 512, W1F, b1F,
                                      counts + t, ridx + (long)t * 16384, U, c0,
                                      mc);
      k_gemm2<<<g2, 256, 0, stream>>>(U, W2F, b2F, counts + t,
                                      ridx + (long)t * 16384, maskF, uwf,
                                      stateF, prevF, c0, mc);
    }
  }
  k_final<<<32896, 256, 0, stream>>>(prevF, nup, rem, d_out, flag);
}

// Round 4
// 3002.065 us; speedup vs baseline: 4.8643x; 1.3991x over previous
//
#include <hip/hip_runtime.h>
#include <hip/hip_bf16.h>
#include <stdint.h>

// ACT (adaptive computation time) on MI355X.
// R4: GEMMs moved from fp32 VALU (45 TF measured, LDS-delivery-capped ~110 TF)
// to bf16x3-split MFMA (6 products hh,mh,lh,hm,mm,hl; split error <=2^-24|x|,
// accumulation error same class/magnitude as the fp32-tiled SGEMM that already
// reproduced every halting decision). Structure: 128x128 tile, BK=32,
// mfma_f32_16x16x32_bf16, wave-tile 64x64 (4x4 of 16x16), pair-shared
// products (24 frag reads -> 96 MFMA per wave per BK), all LDS staging via
// global_load_lds width=16. LDS frag layout [plane][quad][row][16B] ->
// conflict-free contiguous ds_read_b128. Weights pre-transposed+split at
// init; activations pre-split by ponder; U stored as 3 bf16 planes by gemm1.

#define THR 0.99f
typedef float4 f4;
typedef __attribute__((ext_vector_type(8))) short short8;
typedef __attribute__((ext_vector_type(8))) unsigned short us8;
typedef __attribute__((ext_vector_type(4))) float f32x4;

__device__ __forceinline__ float ld_in(const void* p, long i, int bf) {
  if (bf) {
    unsigned short u = ((const unsigned short*)p)[i];
    return __uint_as_float(((unsigned int)u) << 16);
  }
  return ((const float*)p)[i];
}
__device__ __forceinline__ f4 ld4(const float* p) { return *(const f4*)p; }

// truncation 3-way bf16 split: x ~= h + m + l, |err| <= 2^-24|x|
__device__ __forceinline__ void split3(float x, unsigned short& h,
                                       unsigned short& m, unsigned short& l) {
  unsigned u = __float_as_uint(x);
  h = (unsigned short)(u >> 16);
  float fh = __uint_as_float(u & 0xFFFF0000u);
  float r = x - fh;  // exact
  unsigned v = __float_as_uint(r);
  m = (unsigned short)(v >> 16);
  float fm = __uint_as_float(v & 0xFFFF0000u);
  l = (unsigned short)(__float_as_uint(r - fm) >> 16);
}

__device__ __forceinline__ void gld16(const void* g, void* l) {
  __builtin_amdgcn_global_load_lds(
      (const __attribute__((address_space(1))) void*)g,
      (__attribute__((address_space(3))) void*)l, 16, 0, 0);
}

// ---------- dtype detect + small param conversion ----------
__global__ void k_detect(const void* mask, int* flag, const void* emb,
                         const void* Wp, const void* bp, const void* b1,
                         const void* b2, float* embF, float* WpF, float* bpF,
                         float* b1F, float* b2F) {
  __shared__ int sbf;
  if (threadIdx.x == 0) {
    unsigned int u = ((const unsigned int*)mask)[0];
    int bf = (u == 0x3F803F80u) ? 1 : 0;  // two bf16 1.0s vs fp32 1.0
    *flag = bf;
    sbf = bf;
  }
  __syncthreads();
  int bf = sbf;
  for (int i = threadIdx.x; i < 11 * 512; i += 256) embF[i] = ld_in(emb, i, bf);
  for (int i = threadIdx.x; i < 512; i += 256) WpF[i] = ld_in(Wp, i, bf);
  for (int i = threadIdx.x; i < 2048; i += 256) b1F[i] = ld_in(b1, i, bf);
  for (int i = threadIdx.x; i < 512; i += 256) b2F[i] = ld_in(b2, i, bf);
  if (threadIdx.x == 0) bpF[0] = ld_in(bp, 0, bf);
}

// ---------- big conversions + weight transpose/split + zero init ----------
__global__ void k_init(const void* state, const void* W1, const void* W2,
                       const void* mask, const int* flag, float* stateF,
                       unsigned short* w1t, unsigned short* w2t, float* maskF,
                       float* prevF, float* hp, float* rem, float* nup,
                       int* counts) {
  int bf = *flag;
  long t = (long)blockIdx.x * blockDim.x + threadIdx.x;
  long st = (long)gridDim.x * blockDim.x;
  for (long i = t; i < 8388608L; i += st) {
    stateF[i] = ld_in(state, i, bf);
    prevF[i] = 0.f;
  }
  // W1 [512][2048] -> W1T planes [2048][512] bf16 x3 (plane stride 1048576)
  for (long i = t; i < 1048576L; i += st) {
    float v = ld_in(W1, i, bf);
    long n = i & 2047, k = i >> 11;
    unsigned short h, m, l;
    split3(v, h, m, l);
    long o = n * 512 + k;
    w1t[o] = h;
    w1t[1048576L + o] = m;
    w1t[2097152L + o] = l;
  }
  // W2 [2048][512] -> W2T planes [512][2048] bf16 x3
  for (long i = t; i < 1048576L; i += st) {
    float v = ld_in(W2, i, bf);
    long k = i >> 9, n = i & 511;
    unsigned short h, m, l;
    split3(v, h, m, l);
    long o = n * 2048 + k;
    w2t[o] = h;
    w2t[1048576L + o] = m;
    w2t[2097152L + o] = l;
  }
  for (long i = t; i < 16384L; i += st) {
    maskF[i] = ld_in(mask, i, bf);
    hp[i] = 0.f;
    rem[i] = 0.f;
    nup[i] = 0.f;
  }
  if (t < 11) counts[t] = 0;
}

// ---------- ponder: halting chain + compaction + bf16x3 split of s --------
__global__ __launch_bounds__(256) void k_ponder(
    const float* __restrict__ stateF, const float* __restrict__ embF,
    const float* __restrict__ WpF, const float* __restrict__ bpF, float* hp,
    float* rem, float* nup, float* uw, int* __restrict__ count,
    int* __restrict__ ridx, unsigned short* __restrict__ sPl, int t) {
  int lane = threadIdx.x & 63;
  int pos = blockIdx.x * 4 + (threadIdx.x >> 6);
  float hpv = hp[pos];
  if (hpv >= 1.0f) return;  // halted forever
  const float* s = stateF + (long)pos * 512;
  const float* e = embF + t * 512;
  int d = lane * 8;
  f4 s0 = ld4(s + d), s1 = ld4(s + d + 4);
  f4 e0 = ld4(e + d), e1 = ld4(e + d + 4);
  f4 w0 = ld4(WpF + d), w1 = ld4(WpF + d + 4);
  float t0[8];
  t0[0] = s0.x + e0.x; t0[1] = s0.y + e0.y; t0[2] = s0.z + e0.z;
  t0[3] = s0.w + e0.w; t0[4] = s1.x + e1.x; t0[5] = s1.y + e1.y;
  t0[6] = s1.z + e1.z; t0[7] = s1.w + e1.w;
  float acc = t0[0] * w0.x;
  acc = fmaf(t0[1], w0.y, acc);
  acc = fmaf(t0[2], w0.z, acc);
  acc = fmaf(t0[3], w0.w, acc);
  acc = fmaf(t0[4], w1.x, acc);
  acc = fmaf(t0[5], w1.y, acc);
  acc = fmaf(t0[6], w1.z, acc);
  acc = fmaf(t0[7], w1.w, acc);
  // write bf16x3 planes of s (only active rows; gemm gathers via ridx)
  us8 vh, vm, vl;
#pragma unroll
  for (int i = 0; i < 8; i++) {
    unsigned short h, m, l;
    split3(t0[i], h, m, l);
    vh[i] = h; vm[i] = m; vl[i] = l;
  }
  long so = (long)pos * 512 + d;
  *(us8*)(sPl + so) = vh;
  *(us8*)(sPl + 8388608L + so) = vm;
  *(us8*)(sPl + 16777216L + so) = vl;
#pragma unroll
  for (int off = 32; off > 0; off >>= 1) acc += __shfl_xor(acc, off, 64);
  if (lane == 0) {
    float p = 1.0f / (1.0f + expf(-(acc + bpF[0])));
    float q = hpv + p;
    float nh = (q > THR) ? 1.0f : 0.0f;
    float st2 = (q <= THR) ? 1.0f : 0.0f;
    float hpn = hpv + p * st2;
    float remn = rem[pos] + nh * (1.0f - hpn);
    hpn = hpn + nh * remn;
    nup[pos] = nup[pos] + st2 + nh;
    uw[pos] = p * st2 + nh * remn;
    hp[pos] = hpn;
    rem[pos] = remn;
    int idx = atomicAdd(count, 1);
    ridx[idx] = pos;
  }
}

#define MFMA16 __builtin_amdgcn_mfma_f32_16x16x32_bf16

// pair-shared bf16x3 MFMA core: af[3][4] held, B planes streamed
#define CORE_BK()                                                              \
  short8 af[3][4];                                                             \
  _Pragma("unroll") for (int p = 0; p < 3; ++p)                                \
      _Pragma("unroll") for (int mt = 0; mt < 4; ++mt) af[p][mt] =             \
      *(const short8*)&As[p][quad][wm + mt * 16 + ln15][0];                    \
  _Pragma("unroll") for (int pb = 0; pb < 3; ++pb) {                           \
    short8 bfr[4];                                                             \
    _Pragma("unroll") for (int nt = 0; nt < 4; ++nt) bfr[nt] =                 \
        *(const short8*)&Bs[pb][quad][wn + nt * 16 + ln15][0];                 \
    int npa = (pb == 0) ? 3 : ((pb == 1) ? 2 : 1);                             \
    for (int pa = 0; pa < npa; ++pa)                                           \
      _Pragma("unroll") for (int mt = 0; mt < 4; ++mt)                         \
          _Pragma("unroll") for (int nt = 0; nt < 4; ++nt) acc[mt][nt] =       \
          MFMA16(af[pa][mt], bfr[nt], acc[mt][nt], 0, 0, 0);                   \
  }

// ---------- GEMM1: U = relu((s[ridx]) * W1 + b1) -> U bf16x3 planes -------
// A: s planes [16384][512] gathered; B: W1T planes [2048][512]; K=512, N=2048
__global__ __launch_bounds__(256) void k_gemm1(
    const unsigned short* __restrict__ sPl, const unsigned short* __restrict__ w1t,
    const float* __restrict__ b1F, const int* __restrict__ count,
    const int* __restrict__ ridx, unsigned short* __restrict__ uPl,
    long uStride, int c0, int mc) {
  int Ma = *count;
  int mEnd = c0 + mc;
  if (Ma < mEnd) mEnd = Ma;
  int m0 = c0 + blockIdx.x * 128;
  if (m0 >= mEnd) return;
  int n0 = blockIdx.y * 128;
  __shared__ __align__(16) unsigned short As[3][4][128][8];
  __shared__ __align__(16) unsigned short Bs[3][4][128][8];
  int tid = threadIdx.x;
  int lane = tid & 63, wv = tid >> 6;
  int quad = lane >> 4, ln15 = lane & 15;
  int wm = (wv >> 1) << 6, wn = (wv & 1) << 6;
  int rr0 = m0 + lane;
  if (rr0 >= mEnd) rr0 = mEnd - 1;
  int rr1 = m0 + 64 + lane;
  if (rr1 >= mEnd) rr1 = mEnd - 1;
  long pos0 = ridx[rr0], pos1 = ridx[rr1];
  f32x4 acc[4][4];
#pragma unroll
  for (int i = 0; i < 4; i++)
#pragma unroll
    for (int j = 0; j < 4; j++) acc[i][j] = (f32x4)0.f;
#pragma unroll 1
  for (int kt = 0; kt < 16; ++kt) {
    __syncthreads();
#pragma unroll
    for (int i = 0; i < 6; ++i) {  // A staging: j = wv + 4*i over 24 chunks
      int j = wv + 4 * i;
      int p = j >> 3, q = (j >> 1) & 3, hf = j & 1;
      long po = hf ? pos1 : pos0;
      gld16(sPl + (long)p * 8388608L + po * 512 + kt * 32 + q * 8,
            &As[p][q][hf * 64][0]);
    }
#pragma unroll
    for (int i = 0; i < 6; ++i) {  // B staging
      int j = wv + 4 * i;
      int p = j >> 3, q = (j >> 1) & 3, hf = j & 1;
      long n = n0 + hf * 64 + lane;
      gld16(w1t + (long)p * 1048576L + n * 512 + kt * 32 + q * 8,
            &Bs[p][q][hf * 64][0]);
    }
    __syncthreads();
    CORE_BK();
  }
#pragma unroll
  for (int mt = 0; mt < 4; ++mt)
#pragma unroll
    for (int reg = 0; reg < 4; ++reg) {
      int r = m0 + wm + mt * 16 + quad * 4 + reg;
      if (r < mEnd) {
        long lr = r - c0;
#pragma unroll
        for (int nt = 0; nt < 4; ++nt) {
          int n = n0 + wn + nt * 16 + ln15;
          float v = fmaxf(acc[mt][nt][reg] + b1F[n], 0.f);
          unsigned short h, m, l;
          split3(v, h, m, l);
          long o = lr * 2048 + n;
          uPl[o] = h;
          uPl[uStride + o] = m;
          uPl[2 * uStride + o] = l;
        }
      }
    }
}

// ---------- GEMM2: h = U*W2 + b2; state=h*mask; prev += h*uw --------------
// A: U planes [Mc][2048] local rows; B: W2T planes [512][2048]; K=2048, N=512
__global__ __launch_bounds__(256) void k_gemm2(
    const unsigned short* __restrict__ uPl, long uStride,
    const unsigned short* __restrict__ w2t, const float* __restrict__ b2F,
    const int* __restrict__ count, const int* __restrict__ ridx,
    const float* __restrict__ maskF, const float* __restrict__ uwF,
    float* __restrict__ stateF, float* __restrict__ prevF, int c0, int mc) {
  int Ma = *count;
  int mEnd = c0 + mc;
  if (Ma < mEnd) mEnd = Ma;
  int m0 = c0 + blockIdx.x * 128;
  if (m0 >= mEnd) return;
  int n0 = blockIdx.y * 128;
  __shared__ __align__(16) unsigned short As[3][4][128][8];
  __shared__ __align__(16) unsigned short Bs[3][4][128][8];
  int tid = threadIdx.x;
  int lane = tid & 63, wv = tid >> 6;
  int quad = lane >> 4, ln15 = lane & 15;
  int wm = (wv >> 1) << 6, wn = (wv & 1) << 6;
  long lr0 = (long)(m0 - c0) + lane;
  long lr1 = lr0 + 64;
  f32x4 acc[4][4];
#pragma unroll
  for (int i = 0; i < 4; i++)
#pragma unroll
    for (int j = 0; j < 4; j++) acc[i][j] = (f32x4)0.f;
#pragma unroll 1
  for (int kt = 0; kt < 64; ++kt) {
    __syncthreads();
#pragma unroll
    for (int i = 0; i < 6; ++i) {  // A staging (local rows, no gather)
      int j = wv + 4 * i;
      int p = j >> 3, q = (j >> 1) & 3, hf = j & 1;
      long lr = hf ? lr1 : lr0;
      gld16(uPl + (long)p * uStride + lr * 2048 + kt * 32 + q * 8,
            &As[p][q][hf * 64][0]);
    }
#pragma unroll
    for (int i = 0; i < 6; ++i) {  // B staging
      int j = wv + 4 * i;
      int p = j >> 3, q = (j >> 1) & 3, hf = j & 1;
      long n = n0 + hf * 64 + lane;
      gld16(w2t + (long)p * 1048576L + n * 2048 + kt * 32 + q * 8,
            &Bs[p][q][hf * 64][0]);
    }
    __syncthreads();
    CORE_BK();
  }
#pragma unroll
  for (int mt = 0; mt < 4; ++mt)
#pragma unroll
    for (int reg = 0; reg < 4; ++reg) {
      int r = m0 + wm + mt * 16 + quad * 4 + reg;
      if (r < mEnd) {
        long pos = (long)ridx[r];
        float mk = maskF[pos];
        float uv = uwF[pos];
#pragma unroll
        for (int nt = 0; nt < 4; ++nt) {
          int n = n0 + wn + nt * 16 + ln15;
          float h = (acc[mt][nt][reg] + b2F[n]) * mk;
          long off = pos * 512 + n;
          stateF[off] = h;
          prevF[off] = fmaf(h, uv, prevF[off]);
        }
      }
    }
}

// ---------- final: concat outputs, cast per detected dtype ----------
__global__ void k_final(const float* prevF, const float* nupF,
                        const float* remF, void* out, const int* flag) {
  long i = (long)blockIdx.x * 256 + threadIdx.x;
  if (i >= 8421376L) return;
  float v;
  if (i < 8388608L) v = prevF[i];
  else if (i < 8404992L) v = nupF[i - 8388608L];
  else v = remF[i - 8404992L];
  if (*flag) ((__hip_bfloat16*)out)[i] = __float2bfloat16(v);
  else ((float*)out)[i] = v;
}

extern "C" void kernel_launch(void* const* d_in, const int* in_sizes, int n_in,
                              void* d_out, int out_size, void* d_ws,
                              size_t ws_size, hipStream_t stream) {
  const void* state = d_in[0];
  const void* mask = d_in[1];
  const void* emb = d_in[2];
  const void* Wp = d_in[3];
  const void* bp = d_in[4];
  const void* W1 = d_in[5];
  const void* b1 = d_in[6];
  const void* W2 = d_in[7];
  const void* b2 = d_in[8];
  char* w = (char*)d_ws;
  float* stateF = (float*)(w + 0L);
  float* prevF = (float*)(w + 33554432L);
  unsigned short* sPl = (unsigned short*)(w + 67108864L);   // 3 x 16.78 MB
  unsigned short* w1t = (unsigned short*)(w + 117440512L);  // 3 x 2 MB
  unsigned short* w2t = (unsigned short*)(w + 123731968L);  // 3 x 2 MB
  float* maskF = (float*)(w + 130023424L);
  float* hp = (float*)(w + 130088960L);
  float* rem = (float*)(w + 130154496L);
  float* nup = (float*)(w + 130220032L);
  float* uwf = (float*)(w + 130285568L);
  float* embF = (float*)(w + 130351104L);
  float* WpF = (float*)(w + 130416640L);
  float* b1F = (float*)(w + 130420736L);
  float* b2F = (float*)(w + 130428928L);
  float* bpF = (float*)(w + 130433024L);
  int* flag = (int*)(w + 130433152L);
  int* counts = (int*)(w + 130433280L);
  int* ridx = (int*)(w + 130433536L);  // 11 x 16384 x 4 B
  unsigned short* uPl = (unsigned short*)(w + 131154432L);
  // U chunk rows from remaining ws: 3 planes x 2048 bf16 = 12288 B per row
  long ub = (long)ws_size - 131154432L;
  long rows = ub / 12288L;
  long McL = rows & ~127L;
  if (McL > 16384L) McL = 16384L;
  if (McL < 128L) McL = 128L;
  int Mc = (int)McL;
  long uStride = (long)Mc * 2048L;  // elements per plane
  int nCh = (16384 + Mc - 1) / Mc;

  k_detect<<<1, 256, 0, stream>>>(mask, flag, emb, Wp, bp, b1, b2, embF, WpF,
                                  bpF, b1F, b2F);
  k_init<<<2048, 256, 0, stream>>>(state, W1, W2, mask, flag, stateF, w1t, w2t,
                                   maskF, prevF, hp, rem, nup, counts);
  for (int t = 0; t <= 10; t++) {
    k_ponder<<<4096, 256, 0, stream>>>(stateF, embF, WpF, bpF, hp, rem, nup,
                                       uwf, counts + t, ridx + (long)t * 16384,
                                       sPl, t);
    for (int c = 0; c < nCh; c++) {
      int c0 = c * Mc;
      int mc = 16384 - c0;
      if (mc > Mc) mc = Mc;
      dim3 g1(mc / 128, 16), g2(mc / 128, 4);
      k_gemm1<<<g1, 256, 0, stream>>>(sPl, w1t, b1F, counts + t,
                                      ridx + (long)t * 16384, uPl, uStride, c0,
                                      mc);
      k_gemm2<<<g2, 256, 0, stream>>>(uPl, uStride, w2t, b2F, counts + t,
                                      ridx + (long)t * 16384, maskF, uwf,
                                      stateF, prevF, c0, mc);
    }
  }
  k_final<<<32896, 256, 0, stream>>>(prevF, nup, rem, d_out, flag);
}

// Round 5
// 1991.645 us; speedup vs baseline: 7.3321x; 1.5073x over previous
//
#include <hip/hip_runtime.h>
#include <hip/hip_bf16.h>
#include <stdint.h>

// ACT (adaptive computation time) on MI355X.
// R5: bf16x3 MFMA GEMMs, but A-side staged in fp32 and split to 3 bf16 planes
// in registers AFTER the LDS round-trip (bit-identical to splitting before —
// split3 is a pure function). Cuts staging 48->40KB/kt and A global footprint
// 1.5x; removes the sPl/uPl plane buffers entirely (ponder no longer writes
// planes, U is fp32). XCD-pinned 1-D swizzle keeps each XCD's B-strip
// L2-resident (R4 FETCH 460MB vs 207MB unique = B thrash). R4 verified:
// bank conflicts = 0 with [quad][row][16B]-style layouts; bf16x3 reproduces
// every halting decision (absmax stayed at pure bf16 output rounding).

#define THR 0.99f
typedef float4 f4;
typedef __attribute__((ext_vector_type(8))) short short8;
typedef __attribute__((ext_vector_type(4))) float f32x4;

__device__ __forceinline__ float ld_in(const void* p, long i, int bf) {
  if (bf) {
    unsigned short u = ((const unsigned short*)p)[i];
    return __uint_as_float(((unsigned int)u) << 16);
  }
  return ((const float*)p)[i];
}
__device__ __forceinline__ f4 ld4(const float* p) { return *(const f4*)p; }

// truncation 3-way bf16 split: x ~= h + m + l, |err| <= 2^-24|x|
__device__ __forceinline__ void split3(float x, unsigned short& h,
                                       unsigned short& m, unsigned short& l) {
  unsigned u = __float_as_uint(x);
  h = (unsigned short)(u >> 16);
  float fh = __uint_as_float(u & 0xFFFF0000u);
  float r = x - fh;  // exact
  unsigned v = __float_as_uint(r);
  m = (unsigned short)(v >> 16);
  float fm = __uint_as_float(v & 0xFFFF0000u);
  l = (unsigned short)(__float_as_uint(r - fm) >> 16);
}

__device__ __forceinline__ void gld16(const void* g, void* l) {
  __builtin_amdgcn_global_load_lds(
      (const __attribute__((address_space(1))) void*)g,
      (__attribute__((address_space(3))) void*)l, 16, 0, 0);
}

// ---------- dtype detect + small param conversion ----------
__global__ void k_detect(const void* mask, int* flag, const void* emb,
                         const void* Wp, const void* bp, const void* b1,
                         const void* b2, float* embF, float* WpF, float* bpF,
                         float* b1F, float* b2F) {
  __shared__ int sbf;
  if (threadIdx.x == 0) {
    unsigned int u = ((const unsigned int*)mask)[0];
    int bf = (u == 0x3F803F80u) ? 1 : 0;  // two bf16 1.0s vs fp32 1.0
    *flag = bf;
    sbf = bf;
  }
  __syncthreads();
  int bf = sbf;
  for (int i = threadIdx.x; i < 11 * 512; i += 256) embF[i] = ld_in(emb, i, bf);
  for (int i = threadIdx.x; i < 512; i += 256) WpF[i] = ld_in(Wp, i, bf);
  for (int i = threadIdx.x; i < 2048; i += 256) b1F[i] = ld_in(b1, i, bf);
  for (int i = threadIdx.x; i < 512; i += 256) b2F[i] = ld_in(b2, i, bf);
  if (threadIdx.x == 0) bpF[0] = ld_in(bp, 0, bf);
}

// ---------- big conversions + weight transpose/split + zero init ----------
__global__ void k_init(const void* state, const void* W1, const void* W2,
                       const void* mask, const int* flag, float* stateF,
                       unsigned short* w1t, unsigned short* w2t, float* maskF,
                       float* prevF, float* hp, float* rem, float* nup,
                       int* counts) {
  int bf = *flag;
  long t = (long)blockIdx.x * blockDim.x + threadIdx.x;
  long st = (long)gridDim.x * blockDim.x;
  for (long i = t; i < 8388608L; i += st) {
    stateF[i] = ld_in(state, i, bf);
    prevF[i] = 0.f;
  }
  // W1 [512][2048] -> W1T planes [2048][512] bf16 x3 (plane stride 1048576)
  for (long i = t; i < 1048576L; i += st) {
    float v = ld_in(W1, i, bf);
    long n = i & 2047, k = i >> 11;
    unsigned short h, m, l;
    split3(v, h, m, l);
    long o = n * 512 + k;
    w1t[o] = h;
    w1t[1048576L + o] = m;
    w1t[2097152L + o] = l;
  }
  // W2 [2048][512] -> W2T planes [512][2048] bf16 x3
  for (long i = t; i < 1048576L; i += st) {
    float v = ld_in(W2, i, bf);
    long k = i >> 9, n = i & 511;
    unsigned short h, m, l;
    split3(v, h, m, l);
    long o = n * 2048 + k;
    w2t[o] = h;
    w2t[1048576L + o] = m;
    w2t[2097152L + o] = l;
  }
  for (long i = t; i < 16384L; i += st) {
    maskF[i] = ld_in(mask, i, bf);
    hp[i] = 0.f;
    rem[i] = 0.f;
    nup[i] = 0.f;
  }
  if (t < 11) counts[t] = 0;
}

// ---------- pondering + halting update + compaction (1 wave / position) ----
__global__ __launch_bounds__(256) void k_ponder(
    const float* __restrict__ stateF, const float* __restrict__ embF,
    const float* __restrict__ WpF, const float* __restrict__ bpF, float* hp,
    float* rem, float* nup, float* uw, int* __restrict__ count,
    int* __restrict__ ridx, int t) {
  int lane = threadIdx.x & 63;
  int pos = blockIdx.x * 4 + (threadIdx.x >> 6);
  float hpv = hp[pos];
  if (hpv >= 1.0f) return;  // halted forever
  const float* s = stateF + (long)pos * 512;
  const float* e = embF + t * 512;
  int d = lane * 8;
  f4 s0 = ld4(s + d), s1 = ld4(s + d + 4);
  f4 e0 = ld4(e + d), e1 = ld4(e + d + 4);
  f4 w0 = ld4(WpF + d), w1 = ld4(WpF + d + 4);
  float acc = (s0.x + e0.x) * w0.x;
  acc = fmaf(s0.y + e0.y, w0.y, acc);
  acc = fmaf(s0.z + e0.z, w0.z, acc);
  acc = fmaf(s0.w + e0.w, w0.w, acc);
  acc = fmaf(s1.x + e1.x, w1.x, acc);
  acc = fmaf(s1.y + e1.y, w1.y, acc);
  acc = fmaf(s1.z + e1.z, w1.z, acc);
  acc = fmaf(s1.w + e1.w, w1.w, acc);
#pragma unroll
  for (int off = 32; off > 0; off >>= 1) acc += __shfl_xor(acc, off, 64);
  if (lane == 0) {
    float p = 1.0f / (1.0f + expf(-(acc + bpF[0])));
    float q = hpv + p;
    float nh = (q > THR) ? 1.0f : 0.0f;
    float st2 = (q <= THR) ? 1.0f : 0.0f;
    float hpn = hpv + p * st2;
    float remn = rem[pos] + nh * (1.0f - hpn);
    hpn = hpn + nh * remn;
    nup[pos] = nup[pos] + st2 + nh;
    uw[pos] = p * st2 + nh * remn;
    hp[pos] = hpn;
    rem[pos] = remn;
    int idx = atomicAdd(count, 1);
    ridx[idx] = pos;
  }
}

#define MFMA16 __builtin_amdgcn_mfma_f32_16x16x32_bf16

// MFMA product loop: af[3][4] in regs, B planes streamed from LDS.
// products kept: hh, mh, lh, hm, mm, hl (dropped terms <= 2^-24)
#define PROD_LOOP()                                                            \
  _Pragma("unroll") for (int pb = 0; pb < 3; ++pb) {                           \
    short8 bfr[4];                                                             \
    _Pragma("unroll") for (int nt = 0; nt < 4; ++nt) bfr[nt] =                 \
        *(const short8*)&Bs[pb][quad][wn + nt * 16 + ln15][0];                 \
    int npa = (pb == 0) ? 3 : ((pb == 1) ? 2 : 1);                             \
    for (int pa = 0; pa < npa; ++pa)                                           \
      _Pragma("unroll") for (int mt = 0; mt < 4; ++mt)                         \
          _Pragma("unroll") for (int nt = 0; nt < 4; ++nt) acc[mt][nt] =       \
          MFMA16(af[pa][mt], bfr[nt], acc[mt][nt], 0, 0, 0);                   \
  }

// build af[3][4] from fp32 LDS tile (+optional emb add), register split3
#define BUILD_AF(DO_EMB)                                                       \
  short8 af[3][4];                                                             \
  _Pragma("unroll") for (int mt = 0; mt < 4; ++mt) {                           \
    int row = wm + mt * 16 + ln15;                                             \
    f4 x0 = *(const f4*)&Au[quad][0][row][0];                                  \
    f4 x1 = *(const f4*)&Au[quad][1][row][0];                                  \
    float xs[8];                                                               \
    xs[0] = x0.x; xs[1] = x0.y; xs[2] = x0.z; xs[3] = x0.w;                    \
    xs[4] = x1.x; xs[5] = x1.y; xs[6] = x1.z; xs[7] = x1.w;                    \
    if (DO_EMB) {                                                              \
      _Pragma("unroll") for (int j = 0; j < 8; ++j) xs[j] += es[j];            \
    }                                                                          \
    _Pragma("unroll") for (int j = 0; j < 8; ++j) {                            \
      unsigned short h, m, l;                                                  \
      split3(xs[j], h, m, l);                                                  \
      ((unsigned short*)&af[0][mt])[j] = h;                                    \
      ((unsigned short*)&af[1][mt])[j] = m;                                    \
      ((unsigned short*)&af[2][mt])[j] = l;                                    \
    }                                                                          \
  }

// ---------- GEMM1: U = relu((state[ridx]+emb) * W1 + b1) -> U fp32 --------
// A: stateF gathered fp32; B: W1T planes [2048][512]; K=512, N=2048
// 1-D grid (T1*16 blocks), XCD swizzle: 2 B-strips per XCD (768KB, L2-res).
__global__ __launch_bounds__(256) void k_gemm1(
    const float* __restrict__ stateF, const float* __restrict__ embT,
    const unsigned short* __restrict__ w1t, const float* __restrict__ b1F,
    const int* __restrict__ count, const int* __restrict__ ridx,
    float* __restrict__ U, int c0, int mc) {
  int Ma = *count;
  int mEnd = c0 + mc;
  if (Ma < mEnd) mEnd = Ma;
  int f = blockIdx.x;
  int x = f & 7, s = f >> 3;
  int n0 = (x * 2 + (s & 1)) * 128;
  int m0 = c0 + (s >> 1) * 128;
  if (m0 >= mEnd) return;
  __shared__ __align__(16) float Au[4][2][128][4];          // 16 KB fp32 A
  __shared__ __align__(16) unsigned short Bs[3][4][128][8]; // 24 KB B planes
  __shared__ __align__(16) float embS[512];
  int tid = threadIdx.x;
  int lane = tid & 63, wv = tid >> 6;
  int quad = lane >> 4, ln15 = lane & 15;
  int wm = (wv >> 1) << 6, wn = (wv & 1) << 6;
  if (tid < 128) *(f4*)&embS[tid * 4] = ld4(embT + tid * 4);
  int rr0 = m0 + lane;
  if (rr0 >= mEnd) rr0 = mEnd - 1;
  int rr1 = m0 + 64 + lane;
  if (rr1 >= mEnd) rr1 = mEnd - 1;
  long pos0 = ridx[rr0], pos1 = ridx[rr1];
  f32x4 acc[4][4];
#pragma unroll
  for (int i = 0; i < 4; i++)
#pragma unroll
    for (int j = 0; j < 4; j++) acc[i][j] = (f32x4)0.f;
#pragma unroll 1
  for (int kt = 0; kt < 16; ++kt) {
    __syncthreads();
#pragma unroll
    for (int i = 0; i < 4; ++i) {  // A staging fp32: 16 regions of 1KB
      int g = wv + 4 * i;
      int q = g >> 2, h = (g >> 1) & 1, rh = g & 1;
      long po = rh ? pos1 : pos0;
      gld16(stateF + po * 512 + kt * 32 + q * 8 + h * 4,
            &Au[q][h][rh * 64][0]);
    }
#pragma unroll
    for (int i = 0; i < 6; ++i) {  // B staging: 24 regions of 1KB
      int g = wv + 4 * i;
      int p = g >> 3, q = (g >> 1) & 3, rh = g & 1;
      long n = n0 + rh * 64 + lane;
      gld16(w1t + (long)p * 1048576L + n * 512 + kt * 32 + q * 8,
            &Bs[p][q][rh * 64][0]);
    }
    __syncthreads();
    float es[8];
    {
      f4 e0 = *(const f4*)&embS[kt * 32 + quad * 8];
      f4 e1 = *(const f4*)&embS[kt * 32 + quad * 8 + 4];
      es[0] = e0.x; es[1] = e0.y; es[2] = e0.z; es[3] = e0.w;
      es[4] = e1.x; es[5] = e1.y; es[6] = e1.z; es[7] = e1.w;
    }
    BUILD_AF(1);
    PROD_LOOP();
  }
#pragma unroll
  for (int mt = 0; mt < 4; ++mt)
#pragma unroll
    for (int reg = 0; reg < 4; ++reg) {
      int r = m0 + wm + mt * 16 + quad * 4 + reg;
      if (r < mEnd) {
        long lr = r - c0;
#pragma unroll
        for (int nt = 0; nt < 4; ++nt) {
          int n = n0 + wn + nt * 16 + ln15;
          U[lr * 2048 + n] = fmaxf(acc[mt][nt][reg] + b1F[n], 0.f);
        }
      }
    }
}

// ---------- GEMM2: h = U*W2 + b2; state=h*mask; prev += h*uw --------------
// A: U fp32 [Mc][2048] local rows; B: W2T planes [512][2048]; K=2048, N=512
// 1-D grid (T2*4 blocks), XCD swizzle: n0 = (blk&7)>>1 (1.5MB strip, L2-res).
__global__ __launch_bounds__(256) void k_gemm2(
    const float* __restrict__ U, const unsigned short* __restrict__ w2t,
    const float* __restrict__ b2F, const int* __restrict__ count,
    const int* __restrict__ ridx, const float* __restrict__ maskF,
    const float* __restrict__ uwF, float* __restrict__ stateF,
    float* __restrict__ prevF, int c0, int mc) {
  int Ma = *count;
  int mEnd = c0 + mc;
  if (Ma < mEnd) mEnd = Ma;
  int f = blockIdx.x;
  int x = f & 7, s = f >> 3;
  int n0 = (x >> 1) * 128;
  int m0 = c0 + (s * 2 + (x & 1)) * 128;
  if (m0 >= mEnd) return;
  __shared__ __align__(16) float Au[4][2][128][4];          // 16 KB fp32 A
  __shared__ __align__(16) unsigned short Bs[3][4][128][8]; // 24 KB B planes
  int tid = threadIdx.x;
  int lane = tid & 63, wv = tid >> 6;
  int quad = lane >> 4, ln15 = lane & 15;
  int wm = (wv >> 1) << 6, wn = (wv & 1) << 6;
  long lr0 = (long)(m0 - c0) + lane;
  long lr1 = lr0 + 64;
  f32x4 acc[4][4];
#pragma unroll
  for (int i = 0; i < 4; i++)
#pragma unroll
    for (int j = 0; j < 4; j++) acc[i][j] = (f32x4)0.f;
#pragma unroll 1
  for (int kt = 0; kt < 64; ++kt) {
    __syncthreads();
#pragma unroll
    for (int i = 0; i < 4; ++i) {  // A staging fp32
      int g = wv + 4 * i;
      int q = g >> 2, h = (g >> 1) & 1, rh = g & 1;
      long lr = rh ? lr1 : lr0;
      gld16(U + lr * 2048 + kt * 32 + q * 8 + h * 4, &Au[q][h][rh * 64][0]);
    }
#pragma unroll
    for (int i = 0; i < 6; ++i) {  // B staging
      int g = wv + 4 * i;
      int p = g >> 3, q = (g >> 1) & 3, rh = g & 1;
      long n = n0 + rh * 64 + lane;
      gld16(w2t + (long)p * 1048576L + n * 2048 + kt * 32 + q * 8,
            &Bs[p][q][rh * 64][0]);
    }
    __syncthreads();
    float es[8];  // unused in gemm2
    (void)es;
    BUILD_AF(0);
    PROD_LOOP();
  }
#pragma unroll
  for (int mt = 0; mt < 4; ++mt)
#pragma unroll
    for (int reg = 0; reg < 4; ++reg) {
      int r = m0 + wm + mt * 16 + quad * 4 + reg;
      if (r < mEnd) {
        long pos = (long)ridx[r];
        float mk = maskF[pos];
        float uv = uwF[pos];
#pragma unroll
        for (int nt = 0; nt < 4; ++nt) {
          int n = n0 + wn + nt * 16 + ln15;
          float h = (acc[mt][nt][reg] + b2F[n]) * mk;
          long off = pos * 512 + n;
          stateF[off] = h;
          prevF[off] = fmaf(h, uv, prevF[off]);
        }
      }
    }
}

// ---------- final: concat outputs, cast per detected dtype ----------
__global__ void k_final(const float* prevF, const float* nupF,
                        const float* remF, void* out, const int* flag) {
  long i = (long)blockIdx.x * 256 + threadIdx.x;
  if (i >= 8421376L) return;
  float v;
  if (i < 8388608L) v = prevF[i];
  else if (i < 8404992L) v = nupF[i - 8388608L];
  else v = remF[i - 8404992L];
  if (*flag) ((__hip_bfloat16*)out)[i] = __float2bfloat16(v);
  else ((float*)out)[i] = v;
}

extern "C" void kernel_launch(void* const* d_in, const int* in_sizes, int n_in,
                              void* d_out, int out_size, void* d_ws,
                              size_t ws_size, hipStream_t stream) {
  const void* state = d_in[0];
  const void* mask = d_in[1];
  const void* emb = d_in[2];
  const void* Wp = d_in[3];
  const void* bp = d_in[4];
  const void* W1 = d_in[5];
  const void* b1 = d_in[6];
  const void* W2 = d_in[7];
  const void* b2 = d_in[8];
  char* w = (char*)d_ws;
  float* stateF = (float*)(w + 0L);
  float* prevF = (float*)(w + 33554432L);
  unsigned short* w1t = (unsigned short*)(w + 67108864L);  // 3 x 2 MB
  unsigned short* w2t = (unsigned short*)(w + 73400320L);  // 3 x 2 MB
  float* maskF = (float*)(w + 79691776L);
  float* hp = (float*)(w + 79757312L);
  float* rem = (float*)(w + 79822848L);
  float* nup = (float*)(w + 79888384L);
  float* uwf = (float*)(w + 79953920L);
  float* embF = (float*)(w + 80019456L);
  float* WpF = (float*)(w + 80052224L);
  float* b1F = (float*)(w + 80056320L);
  float* b2F = (float*)(w + 80064512L);
  float* bpF = (float*)(w + 80068608L);
  int* flag = (int*)(w + 80068864L);
  int* counts = (int*)(w + 80069120L);
  int* ridx = (int*)(w + 80070144L);  // 11 x 16384 x 4 B
  float* U = (float*)(w + 80791040L); // fp32 [Mc][2048]
  long ub = (long)ws_size - 80791040L;
  long rows = ub / 8192L;
  long McL = rows & ~255L;  // multiple of 256 so T=mc/128 stays even
  if (McL > 16384L) McL = 16384L;
  if (McL < 256L) McL = 256L;
  int Mc = (int)McL;
  int nCh = (16384 + Mc - 1) / Mc;

  k_detect<<<1, 256, 0, stream>>>(mask, flag, emb, Wp, bp, b1, b2, embF, WpF,
                                  bpF, b1F, b2F);
  k_init<<<2048, 256, 0, stream>>>(state, W1, W2, mask, flag, stateF, w1t, w2t,
                                   maskF, prevF, hp, rem, nup, counts);
  for (int t = 0; t <= 10; t++) {
    k_ponder<<<4096, 256, 0, stream>>>(stateF, embF, WpF, bpF, hp, rem, nup,
                                       uwf, counts + t, ridx + (long)t * 16384,
                                       t);
    for (int c = 0; c < nCh; c++) {
      int c0 = c * Mc;
      int mc = 16384 - c0;
      if (mc > Mc) mc = Mc;
      int T = mc / 128;  // even (Mc multiple of 256, 16384 multiple of 256)
      k_gemm1<<<T * 16, 256, 0, stream>>>(stateF, embF + t * 512, w1t, b1F,
                                          counts + t, ridx + (long)t * 16384,
                                          U, c0, mc);
      k_gemm2<<<T * 4, 256, 0, stream>>>(U, w2t, b2F, counts + t,
                                         ridx + (long)t * 16384, maskF, uwf,
                                         stateF, prevF, c0, mc);
    }
  }
  k_final<<<32896, 256, 0, stream>>>(prevF, nup, rem, d_out, flag);
}